// Round 10
// baseline (393.750 us; speedup 1.0000x reference)
//
#include <hip/hip_runtime.h>
#include <hip/hip_cooperative_groups.h>

namespace cg = cooperative_groups;

typedef float f32x4 __attribute__((ext_vector_type(4)));

// Problem dims (fixed by reference): bs=4, L=512, H=768, C=48
#define H_DIM 768
#define C_DIM 48
#define NROWS 2048          // bs * L
#define TWO_H 1536

// GEMM geometry (R9 proven: BM=64, KS=8, 256 working blocks)
#define BM 64
#define BK 32
#define KSLICE 96
#define NSTEP (KSLICE / BK)   // 3
#define KS 8
#define LDA 33
#define LDB 33
#define PART_ELEMS (KS * NROWS * 96)   // 1572864 floats (6.29 MB)
#define GRID 1024                      // 4 blocks/CU co-resident

// ---------------------------------------------------------------------------
// ONE cooperative kernel, three phases separated by grid.sync():
//  A (blocks 0..255):  split-k GEMM, B staged directly from W w/ transpose.
//                      Single-buffered LDS (21.1 KB) + register prefetch —
//                      same 2-barrier-per-step schedule as R9, half the LDS.
//  B (blocks 0..191):  reduce 8 k-slice partials -> proj[half][row][c].
//  C (all 1024):       out[b,i,j,c] = proj_i + proj_j + bias, 2 rows/block.
//                      rowi kept in 3 regs/thread (c4 = (t+4*(it%3))%12).
// ---------------------------------------------------------------------------
__global__ __launch_bounds__(256, 4) void fused_kernel(
    const float* __restrict__ hs, const float* __restrict__ W,
    const float* __restrict__ bias, float* __restrict__ out,
    float* __restrict__ proj, float* __restrict__ part) {

    cg::grid_group grid = cg::this_grid();

    __shared__ float A_lds[BM][LDA];   // 8.4 KB
    __shared__ float B_lds[96][LDB];   // 12.7 KB

    const int t   = threadIdx.x;
    const int blk = blockIdx.x;

    // ================= Phase A: split-k GEMM =================
    if (blk < 256) {
        const int kg    = blk & 7;
        const int rg    = blk >> 3;
        const int row0  = rg * BM;
        const int kbase = kg * KSLICE;

        const int r4 = t >> 4;             // 0..15 (4 rows each)
        const int c6 = t & 15;             // 0..15 (6 cols each)
        const int a_row = t >> 3;          // 0..31
        const int a_kf4 = t & 7;           // 0..7

        const f32x4* __restrict__ hs4 = reinterpret_cast<const f32x4*>(hs);

        f32x4 a_reg[2], b_reg[3];

        // prefetch step 0 into regs
        {
            const int k0 = kbase;
            #pragma unroll
            for (int i = 0; i < 2; ++i)
                a_reg[i] = hs4[(size_t)(row0 + a_row + i * 32) * (H_DIM / 4) + (k0 >> 2) + a_kf4];
            #pragma unroll
            for (int q = 0; q < 3; ++q) {
                const int idx  = q * 256 + t;
                const int c    = idx >> 3;
                const int kf4  = idx & 7;
                const int half = c / C_DIM;
                const int cc   = c - half * C_DIM;
                b_reg[q] = *reinterpret_cast<const f32x4*>(
                    W + (size_t)cc * TWO_H + (size_t)half * H_DIM + k0 + kf4 * 4);
            }
        }

        float acc[4][6];
        #pragma unroll
        for (int ri = 0; ri < 4; ++ri)
            #pragma unroll
            for (int j = 0; j < 6; ++j) acc[ri][j] = 0.f;

        for (int s = 0; s < NSTEP; ++s) {
            if (s) __syncthreads();        // previous compute done

            // regs -> LDS
            #pragma unroll
            for (int i = 0; i < 2; ++i)
                *reinterpret_cast<f32x4*>(&A_lds[a_row + i * 32][a_kf4 * 4]) = a_reg[i];
            #pragma unroll
            for (int q = 0; q < 3; ++q) {
                const int idx = q * 256 + t;
                const int c   = idx >> 3;
                const int kf4 = idx & 7;
                *reinterpret_cast<f32x4*>(&B_lds[c][kf4 * 4]) = b_reg[q];
            }
            __syncthreads();

            // prefetch step s+1 (overlaps compute)
            if (s + 1 < NSTEP) {
                const int k0 = kbase + (s + 1) * BK;
                #pragma unroll
                for (int i = 0; i < 2; ++i)
                    a_reg[i] = hs4[(size_t)(row0 + a_row + i * 32) * (H_DIM / 4) + (k0 >> 2) + a_kf4];
                #pragma unroll
                for (int q = 0; q < 3; ++q) {
                    const int idx  = q * 256 + t;
                    const int c    = idx >> 3;
                    const int kf4  = idx & 7;
                    const int half = c / C_DIM;
                    const int cc   = c - half * C_DIM;
                    b_reg[q] = *reinterpret_cast<const f32x4*>(
                        W + (size_t)cc * TWO_H + (size_t)half * H_DIM + k0 + kf4 * 4);
                }
            }

            // compute step s from LDS
            #pragma unroll
            for (int kk4 = 0; kk4 < BK / 4; ++kk4) {
                f32x4 a[4], b[6];
                #pragma unroll
                for (int ri = 0; ri < 4; ++ri)
                    a[ri] = *reinterpret_cast<const f32x4*>(&A_lds[r4 * 4 + ri][kk4 * 4]);
                #pragma unroll
                for (int j = 0; j < 6; ++j)
                    b[j] = *reinterpret_cast<const f32x4*>(&B_lds[c6 * 6 + j][kk4 * 4]);
                #pragma unroll
                for (int ri = 0; ri < 4; ++ri)
                    #pragma unroll
                    for (int j = 0; j < 6; ++j) {
                        acc[ri][j] += a[ri].x * b[j].x;
                        acc[ri][j] += a[ri].y * b[j].y;
                        acc[ri][j] += a[ri].z * b[j].z;
                        acc[ri][j] += a[ri].w * b[j].w;
                    }
            }
        }

        // epilogue: partial slab
        float* __restrict__ pslab = part + (size_t)kg * (NROWS * 96);
        #pragma unroll
        for (int ri = 0; ri < 4; ++ri) {
            const int row = row0 + r4 * 4 + ri;
            #pragma unroll
            for (int j = 0; j < 6; ++j)
                pslab[(size_t)row * 96 + c6 * 6 + j] = acc[ri][j];
        }
    }

    __threadfence();
    grid.sync();

    // ================= Phase B: reduce partials =================
    if (blk < 192) {
        const int p = blk * 256 + t;                  // 0..49151
        const f32x4* __restrict__ part4 = reinterpret_cast<const f32x4*>(part);
        f32x4 v = part4[p];
        #pragma unroll
        for (int g = 1; g < KS; ++g)
            v += part4[(size_t)g * (NROWS * 24) + p];
        const int row  = p / 24;
        const int c4   = p % 24;
        const int half = c4 / 12;
        const int cl4  = c4 % 12;
        reinterpret_cast<f32x4*>(proj)[(size_t)half * (NROWS * 12) + (size_t)row * 12 + cl4] = v;
    }

    __threadfence();
    grid.sync();

    // ================= Phase C: broadcast-add (2 rows/block) =================
    {
        const int tm12 = t % 12;
        f32x4 bb[3];
        #pragma unroll
        for (int q = 0; q < 3; ++q)
            bb[q] = reinterpret_cast<const f32x4*>(bias)[(tm12 + 4 * q) % 12];

        #pragma unroll
        for (int rr = 0; rr < 2; ++rr) {
            const int gi = blk * 2 + rr;              // 0..2047
            const int b  = gi >> 9;

            f32x4 ri[3];
            #pragma unroll
            for (int q = 0; q < 3; ++q)
                ri[q] = reinterpret_cast<const f32x4*>(proj + (size_t)gi * C_DIM)
                            [(tm12 + 4 * q) % 12] + bb[q];

            const f32x4* __restrict__ pj =
                reinterpret_cast<const f32x4*>(proj + (size_t)NROWS * C_DIM
                                                    + (size_t)b * 512 * C_DIM);
            f32x4* __restrict__ o =
                reinterpret_cast<f32x4*>(out) + (size_t)gi * 6144;

            #pragma unroll
            for (int it = 0; it < 24; ++it) {
                const int p = it * 256 + t;
                o[p] = pj[p] + ri[it % 3];
            }
        }
    }
}

// ---------------------------------------------------------------------------
// Fallback (R9 proven path) in case cooperative launch is rejected.
// ---------------------------------------------------------------------------
__global__ __launch_bounds__(256) void pgemm_kernel(const float* __restrict__ hs,
                                                    const float* __restrict__ W,
                                                    float* __restrict__ part) {
    __shared__ float A_lds[2][BM][LDA];
    __shared__ float B_lds[2][96][LDB];

    const int t     = threadIdx.x;
    const int kg    = blockIdx.x & 7;
    const int rg    = blockIdx.x >> 3;
    const int row0  = rg * BM;
    const int kbase = kg * KSLICE;
    const int r4 = t >> 4;
    const int c6 = t & 15;
    const f32x4* __restrict__ hs4 = reinterpret_cast<const f32x4*>(hs);
    const int a_row = t >> 3;
    const int a_kf4 = t & 7;

    f32x4 a_reg[2], b_reg[3];
    {
        const int k0 = kbase;
        #pragma unroll
        for (int i = 0; i < 2; ++i)
            a_reg[i] = hs4[(size_t)(row0 + a_row + i * 32) * (H_DIM / 4) + (k0 >> 2) + a_kf4];
        #pragma unroll
        for (int q = 0; q < 3; ++q) {
            const int idx = q * 256 + t; const int c = idx >> 3; const int kf4 = idx & 7;
            const int half = c / C_DIM; const int cc = c - half * C_DIM;
            b_reg[q] = *reinterpret_cast<const f32x4*>(
                W + (size_t)cc * TWO_H + (size_t)half * H_DIM + k0 + kf4 * 4);
        }
    }
    {
        #pragma unroll
        for (int i = 0; i < 2; ++i)
            *reinterpret_cast<f32x4*>(&A_lds[0][a_row + i * 32][a_kf4 * 4]) = a_reg[i];
        #pragma unroll
        for (int q = 0; q < 3; ++q) {
            const int idx = q * 256 + t; const int c = idx >> 3; const int kf4 = idx & 7;
            *reinterpret_cast<f32x4*>(&B_lds[0][c][kf4 * 4]) = b_reg[q];
        }
    }

    float acc[4][6];
    #pragma unroll
    for (int ri = 0; ri < 4; ++ri)
        #pragma unroll
        for (int j = 0; j < 6; ++j) acc[ri][j] = 0.f;

    for (int s = 0; s < NSTEP; ++s) {
        __syncthreads();
        if (s + 1 < NSTEP) {
            const int k0 = kbase + (s + 1) * BK;
            #pragma unroll
            for (int i = 0; i < 2; ++i)
                a_reg[i] = hs4[(size_t)(row0 + a_row + i * 32) * (H_DIM / 4) + (k0 >> 2) + a_kf4];
            #pragma unroll
            for (int q = 0; q < 3; ++q) {
                const int idx = q * 256 + t; const int c = idx >> 3; const int kf4 = idx & 7;
                const int half = c / C_DIM; const int cc = c - half * C_DIM;
                b_reg[q] = *reinterpret_cast<const f32x4*>(
                    W + (size_t)cc * TWO_H + (size_t)half * H_DIM + k0 + kf4 * 4);
            }
        }
        const int buf = s & 1;
        #pragma unroll
        for (int kk4 = 0; kk4 < BK / 4; ++kk4) {
            f32x4 a[4], b[6];
            #pragma unroll
            for (int ri = 0; ri < 4; ++ri)
                a[ri] = *reinterpret_cast<const f32x4*>(&A_lds[buf][r4 * 4 + ri][kk4 * 4]);
            #pragma unroll
            for (int j = 0; j < 6; ++j)
                b[j] = *reinterpret_cast<const f32x4*>(&B_lds[buf][c6 * 6 + j][kk4 * 4]);
            #pragma unroll
            for (int ri = 0; ri < 4; ++ri)
                #pragma unroll
                for (int j = 0; j < 6; ++j) {
                    acc[ri][j] += a[ri].x * b[j].x;
                    acc[ri][j] += a[ri].y * b[j].y;
                    acc[ri][j] += a[ri].z * b[j].z;
                    acc[ri][j] += a[ri].w * b[j].w;
                }
        }
        __syncthreads();
        if (s + 1 < NSTEP) {
            const int buf2 = (s + 1) & 1;
            #pragma unroll
            for (int i = 0; i < 2; ++i)
                *reinterpret_cast<f32x4*>(&A_lds[buf2][a_row + i * 32][a_kf4 * 4]) = a_reg[i];
            #pragma unroll
            for (int q = 0; q < 3; ++q) {
                const int idx = q * 256 + t; const int c = idx >> 3; const int kf4 = idx & 7;
                *reinterpret_cast<f32x4*>(&B_lds[buf2][c][kf4 * 4]) = b_reg[q];
            }
        }
    }

    float* __restrict__ pslab = part + (size_t)kg * (NROWS * 96);
    #pragma unroll
    for (int ri = 0; ri < 4; ++ri) {
        const int row = row0 + r4 * 4 + ri;
        #pragma unroll
        for (int j = 0; j < 6; ++j)
            pslab[(size_t)row * 96 + c6 * 6 + j] = acc[ri][j];
    }
}

__global__ __launch_bounds__(256) void preduce_kernel(const float* __restrict__ part,
                                                      float* __restrict__ proj) {
    const int p = blockIdx.x * 256 + threadIdx.x;
    const f32x4* __restrict__ part4 = reinterpret_cast<const f32x4*>(part);
    f32x4 v = part4[p];
    #pragma unroll
    for (int g = 1; g < 8; ++g)
        v += part4[(size_t)g * (NROWS * 24) + p];
    const int row = p / 24; const int c4 = p % 24;
    const int half = c4 / 12; const int cl4 = c4 % 12;
    reinterpret_cast<f32x4*>(proj)[(size_t)half * (NROWS * 12) + (size_t)row * 12 + cl4] = v;
}

__global__ __launch_bounds__(256) void bcast_kernel(const float* __restrict__ proj,
                                                    const float* __restrict__ bias,
                                                    float* __restrict__ out) {
    const int gi = blockIdx.x;
    const int b  = gi >> 9;
    __shared__ f32x4 rowi[C_DIM / 4];
    const int t = threadIdx.x;
    if (t < C_DIM / 4) {
        f32x4 pi = reinterpret_cast<const f32x4*>(proj + (size_t)gi * C_DIM)[t];
        f32x4 bb = reinterpret_cast<const f32x4*>(bias)[t];
        rowi[t] = pi + bb;
    }
    __syncthreads();
    const f32x4* __restrict__ pj =
        reinterpret_cast<const f32x4*>(proj + (size_t)NROWS * C_DIM + (size_t)b * 512 * C_DIM);
    f32x4* __restrict__ o = reinterpret_cast<f32x4*>(out) + (size_t)gi * 6144;
    #pragma unroll
    for (int it = 0; it < 24; ++it) {
        const int p = it * 256 + t;
        o[p] = pj[p] + rowi[p % 12];
    }
}

extern "C" void kernel_launch(void* const* d_in, const int* in_sizes, int n_in,
                              void* d_out, int out_size, void* d_ws, size_t ws_size,
                              hipStream_t stream) {
    const float* hs   = (const float*)d_in[0];   // (4, 512, 768) f32
    const float* W    = (const float*)d_in[1];   // (48, 1536)    f32
    const float* bias = (const float*)d_in[2];   // (48,)         f32
    float* out  = (float*)d_out;                 // (4,512,512,48) f32
    float* proj = (float*)d_ws;                  // 786 KB in workspace

    // part lives in the d_out tail (consumed in phase B before phase C
    // overwrites it). No memsets, no atomics.
    float* part = out + (size_t)out_size - PART_ELEMS;

    void* args[] = {(void*)&hs, (void*)&W, (void*)&bias,
                    (void*)&out, (void*)&proj, (void*)&part};
    hipError_t err = hipLaunchCooperativeKernel(
        reinterpret_cast<void*>(fused_kernel),
        dim3(GRID), dim3(256), args, 0, stream);

    if (err != hipSuccess) {
        // Deterministic fallback: proven R9 3-kernel path.
        pgemm_kernel<<<dim3(256), 256, 0, stream>>>(hs, W, part);
        preduce_kernel<<<dim3(192), 256, 0, stream>>>(part, proj);
        bcast_kernel<<<dim3(NROWS), 256, 0, stream>>>(proj, bias, out);
    }
}

// Round 11
// 49.120 us; speedup vs baseline: 8.0161x; 8.0161x over previous
//
#include <hip/hip_runtime.h>

typedef float f32x4 __attribute__((ext_vector_type(4)));

// Problem dims (fixed by reference): bs=4, L=512, H=768, C=48
#define H_DIM 768
#define C_DIM 48
#define NROWS 2048          // bs * L
#define TWO_H 1536

// pgemm geometry (R9 proven: BM=64, KS=8, 256 blocks, 1/CU)
#define BM 64
#define BK 32
#define KSLICE 96
#define NSTEP (KSLICE / BK)   // 3
#define KS 8
// LDS row strides: 36 words = 144 B -> every f32x4 (b128) access 16-B aligned.
// Banks: A-reads (rows 4 apart, stride 144w%32=16) -> 2 addrs/bank-quad = free;
// B-reads (cols 16 apart via c6+16j, stride 36w%32=4) -> 2-way = free (m136).
#define LDA 36
#define LDB 36
#define PART_ELEMS (KS * NROWS * 96)   // 1572864 floats (6.29 MB)

// ---------------------------------------------------------------------------
// Kernel 1: split-k tiled GEMM, B staged DIRECTLY from W with on-the-fly
// transpose. part[kg][row][c] = sum_{k in kg-slice} hs[row][k] * Wcol(c)[k]
//   Wcol(c)[k] = W[c][k] (c<48) ; W[c-48][768+k] (c>=48)
// grid = 32 rowgroups x 8 k-slices = 256 blocks (1/CU), block = 256 threads.
// Thread tile: 4 rows (r4) x 6 cols (c6 + 16j interleaved).
// ---------------------------------------------------------------------------
__global__ __launch_bounds__(256) void pgemm_kernel(const float* __restrict__ hs,
                                                    const float* __restrict__ W,
                                                    float* __restrict__ part) {
    __shared__ float A_lds[2][BM][LDA];   // 2 x 9.2 KB
    __shared__ float B_lds[2][96][LDB];   // 2 x 13.8 KB

    const int t     = threadIdx.x;
    const int kg    = blockIdx.x & 7;     // k-slice 0..7
    const int rg    = blockIdx.x >> 3;    // rowgroup 0..31
    const int row0  = rg * BM;
    const int kbase = kg * KSLICE;

    const int r4 = t >> 4;                // 0..15 (4 rows each)
    const int c6 = t & 15;                // 0..15 (cols c6+16j, j=0..5)

    const f32x4* __restrict__ hs4 = reinterpret_cast<const f32x4*>(hs);

    // Staging roles. A: rows a_row, a_row+32; B: 3 f32x4/thread from W rows.
    const int a_row = t >> 3;             // 0..31
    const int a_kf4 = t & 7;              // 0..7

    f32x4 a_reg[2], b_reg[3];

    // ---- load step 0 into regs ----
    {
        const int k0 = kbase;
        #pragma unroll
        for (int i = 0; i < 2; ++i)
            a_reg[i] = hs4[(size_t)(row0 + a_row + i * 32) * (H_DIM / 4) + (k0 >> 2) + a_kf4];
        #pragma unroll
        for (int q = 0; q < 3; ++q) {
            const int idx  = q * 256 + t;  // 0..767
            const int c    = idx >> 3;     // 0..95
            const int kf4  = idx & 7;      // 0..7
            const int half = c / C_DIM;
            const int cc   = c - half * C_DIM;
            b_reg[q] = *reinterpret_cast<const f32x4*>(
                W + (size_t)cc * TWO_H + (size_t)half * H_DIM + k0 + kf4 * 4);
        }
    }
    // ---- write step 0 to LDS buf 0 ----
    {
        #pragma unroll
        for (int i = 0; i < 2; ++i)
            *reinterpret_cast<f32x4*>(&A_lds[0][a_row + i * 32][a_kf4 * 4]) = a_reg[i];
        #pragma unroll
        for (int q = 0; q < 3; ++q) {
            const int idx = q * 256 + t;
            const int c   = idx >> 3;
            const int kf4 = idx & 7;
            *reinterpret_cast<f32x4*>(&B_lds[0][c][kf4 * 4]) = b_reg[q];
        }
    }

    float acc[4][6];
    #pragma unroll
    for (int ri = 0; ri < 4; ++ri)
        #pragma unroll
        for (int j = 0; j < 6; ++j) acc[ri][j] = 0.f;

    for (int s = 0; s < NSTEP; ++s) {
        __syncthreads();

        // Prefetch step s+1 into regs (overlaps with compute below).
        if (s + 1 < NSTEP) {
            const int k0 = kbase + (s + 1) * BK;
            #pragma unroll
            for (int i = 0; i < 2; ++i)
                a_reg[i] = hs4[(size_t)(row0 + a_row + i * 32) * (H_DIM / 4) + (k0 >> 2) + a_kf4];
            #pragma unroll
            for (int q = 0; q < 3; ++q) {
                const int idx  = q * 256 + t;
                const int c    = idx >> 3;
                const int kf4  = idx & 7;
                const int half = c / C_DIM;
                const int cc   = c - half * C_DIM;
                b_reg[q] = *reinterpret_cast<const f32x4*>(
                    W + (size_t)cc * TWO_H + (size_t)half * H_DIM + k0 + kf4 * 4);
            }
        }

        // Compute step s from LDS (all b128, 16-B aligned).
        const int buf = s & 1;
        #pragma unroll
        for (int kk4 = 0; kk4 < BK / 4; ++kk4) {
            f32x4 a[4], b[6];
            #pragma unroll
            for (int ri = 0; ri < 4; ++ri)
                a[ri] = *reinterpret_cast<const f32x4*>(&A_lds[buf][r4 * 4 + ri][kk4 * 4]);
            #pragma unroll
            for (int j = 0; j < 6; ++j)
                b[j] = *reinterpret_cast<const f32x4*>(&B_lds[buf][c6 + j * 16][kk4 * 4]);
            #pragma unroll
            for (int ri = 0; ri < 4; ++ri)
                #pragma unroll
                for (int j = 0; j < 6; ++j) {
                    acc[ri][j] += a[ri].x * b[j].x;
                    acc[ri][j] += a[ri].y * b[j].y;
                    acc[ri][j] += a[ri].z * b[j].z;
                    acc[ri][j] += a[ri].w * b[j].w;
                }
        }

        __syncthreads();

        // Write prefetched regs into the other LDS buffer.
        if (s + 1 < NSTEP) {
            const int buf2 = (s + 1) & 1;
            #pragma unroll
            for (int i = 0; i < 2; ++i)
                *reinterpret_cast<f32x4*>(&A_lds[buf2][a_row + i * 32][a_kf4 * 4]) = a_reg[i];
            #pragma unroll
            for (int q = 0; q < 3; ++q) {
                const int idx = q * 256 + t;
                const int c   = idx >> 3;
                const int kf4 = idx & 7;
                *reinterpret_cast<f32x4*>(&B_lds[buf2][c][kf4 * 4]) = b_reg[q];
            }
        }
    }

    // Epilogue: write the 4x6 tile to this k-slice's partial slab.
    // col = c6 + 16j -> lanes 0..15 write 64-B contiguous runs per j.
    float* __restrict__ pslab = part + (size_t)kg * (NROWS * 96);
    #pragma unroll
    for (int ri = 0; ri < 4; ++ri) {
        const int row = row0 + r4 * 4 + ri;
        #pragma unroll
        for (int j = 0; j < 6; ++j)
            pslab[(size_t)row * 96 + c6 + j * 16] = acc[ri][j];
    }
}

// ---------------------------------------------------------------------------
// Kernel 1b: reduce 8 k-slice partials -> proj[half][row][cl]
// 49152 f32x4 outputs; grid = 192 x 256, one f32x4 per thread.
// ---------------------------------------------------------------------------
__global__ __launch_bounds__(256) void preduce_kernel(const float* __restrict__ part,
                                                      float* __restrict__ proj) {
    const int p = blockIdx.x * 256 + threadIdx.x;     // 0..49151
    const f32x4* __restrict__ part4 = reinterpret_cast<const f32x4*>(part);

    f32x4 v = part4[p];
    #pragma unroll
    for (int g = 1; g < 8; ++g)
        v += part4[(size_t)g * (NROWS * 24) + p];

    const int row  = p / 24;
    const int c4   = p % 24;
    const int half = c4 / 12;
    const int cl4  = c4 % 12;
    reinterpret_cast<f32x4*>(proj)[(size_t)half * (NROWS * 12) + (size_t)row * 12 + cl4] = v;
}

// ---------------------------------------------------------------------------
// Kernel 2: out[b,i,j,c] = proj_i[b,i,c] + proj_j[b,j,c] + bias[c]
// R4 version (best measured): one block per (b,i), 2048 x 256.
// ---------------------------------------------------------------------------
__global__ __launch_bounds__(256) void bcast_kernel(const float* __restrict__ proj,
                                                    const float* __restrict__ bias,
                                                    float* __restrict__ out) {
    const int gi = blockIdx.x;          // b*512 + i
    const int b  = gi >> 9;

    __shared__ f32x4 rowi[C_DIM / 4];   // proj_i[b,i,:] + bias  (12 f32x4)

    const int t = threadIdx.x;
    if (t < C_DIM / 4) {
        f32x4 pi = reinterpret_cast<const f32x4*>(proj + (size_t)gi * C_DIM)[t];
        f32x4 bb = reinterpret_cast<const f32x4*>(bias)[t];
        rowi[t] = pi + bb;
    }
    __syncthreads();

    const f32x4* __restrict__ pj =
        reinterpret_cast<const f32x4*>(proj + (size_t)NROWS * C_DIM
                                            + (size_t)b * 512 * C_DIM);
    f32x4* __restrict__ o =
        reinterpret_cast<f32x4*>(out) + (size_t)gi * 6144;

    #pragma unroll
    for (int it = 0; it < 24; ++it) {
        const int p  = it * 256 + t;
        o[p] = pj[p] + rowi[p % 12];
    }
}

extern "C" void kernel_launch(void* const* d_in, const int* in_sizes, int n_in,
                              void* d_out, int out_size, void* d_ws, size_t ws_size,
                              hipStream_t stream) {
    const float* hs   = (const float*)d_in[0];   // (4, 512, 768) f32
    const float* W    = (const float*)d_in[1];   // (48, 1536)    f32
    const float* bias = (const float*)d_in[2];   // (48,)         f32
    float* out  = (float*)d_out;                 // (4,512,512,48) f32
    float* proj = (float*)d_ws;                  // 786 KB in workspace

    // part lives in the d_out tail (consumed by preduce before bcast
    // overwrites it). No memsets, no atomics, no cooperative launch.
    float* part = out + (size_t)out_size - PART_ELEMS;

    pgemm_kernel<<<dim3(256), 256, 0, stream>>>(hs, W, part);
    preduce_kernel<<<dim3(192), 256, 0, stream>>>(part, proj);
    bcast_kernel<<<dim3(NROWS), 256, 0, stream>>>(proj, bias, out);
}

// Round 12
// 47.775 us; speedup vs baseline: 8.2418x; 1.0282x over previous
//
#include <hip/hip_runtime.h>

typedef float f32x4 __attribute__((ext_vector_type(4)));

// Problem dims (fixed by reference): bs=4, L=512, H=768, C=48
#define H_DIM 768
#define C_DIM 48
#define NROWS 2048          // bs * L
#define TWO_H 1536

// gemm geometry: 256 blocks = 128 rowgroups x 2 halves; 256 thr = 2 k-groups.
#define GBM 16              // rows per block
#define GBK 128             // staged k per step (shared by both k-groups)
#define GNSTEP (H_DIM / GBK)  // 6
#define GLDA 132            // 128 + 4 pad words; 528 B row stride (16B-aligned)
#define GLDB 132
#define MT_LD 52            // merge-tile row stride (208 B, 16B-aligned)

// ---------------------------------------------------------------------------
// Kernel 1: proj GEMM, no global partials.
//   block(rg, half): rows rg*16..+16, cols half*48..+48 of the fused [96] GEMM
//   thread: kgrp = t>>7 (k 0..383 / 384..767), slot tt=t&127 -> 2x3 reg tile
//   K-loop: 6 steps of BK=128 staged once (A 8KB + B 24KB, double-buffered,
//   register-prefetched); group g computes kk4 in [16g, 16g+16).
//   Merge: g1 -> mtile, g0 adds, coalesced write to proj. One kernel, done.
// ---------------------------------------------------------------------------
__global__ __launch_bounds__(256) void gemm_kernel(const float* __restrict__ hs,
                                                   const float* __restrict__ W,
                                                   float* __restrict__ proj) {
    __shared__ float A_lds[2][GBM][GLDA];     // 16.9 KB
    __shared__ float B_lds[2][C_DIM][GLDB];   // 50.7 KB
    __shared__ float mtile[GBM][MT_LD];       // 3.3 KB

    const int t    = threadIdx.x;
    const int half = blockIdx.x & 1;
    const int rg   = blockIdx.x >> 1;         // 0..127
    const int row0 = rg * GBM;

    const int kgrp = t >> 7;                  // 0..1
    const int tt   = t & 127;
    const int rs   = tt >> 4;                 // 0..7  (rows rs*2, rs*2+1)
    const int cs   = tt & 15;                 // 0..15 (cols cs*3..+2)

    const f32x4* __restrict__ hs4 = reinterpret_cast<const f32x4*>(hs);
    const float* __restrict__ Wh  = W + (size_t)half * H_DIM;

    f32x4 a_reg[2], b_reg[6];

    // ---- load step 0 into regs ----
    {
        const int k0 = 0;
        #pragma unroll
        for (int q = 0; q < 2; ++q) {
            const int idx = q * 256 + t;       // 0..511
            const int row = idx >> 5;          // 0..15
            const int kf4 = idx & 31;          // 0..31
            a_reg[q] = hs4[(size_t)(row0 + row) * (H_DIM / 4) + (k0 >> 2) + kf4];
        }
        #pragma unroll
        for (int q = 0; q < 6; ++q) {
            const int idx = q * 256 + t;       // 0..1535
            const int c   = idx >> 5;          // 0..47
            const int kf4 = idx & 31;
            b_reg[q] = *reinterpret_cast<const f32x4*>(
                Wh + (size_t)c * TWO_H + k0 + kf4 * 4);
        }
    }
    // ---- write step 0 to LDS buf 0 ----
    {
        #pragma unroll
        for (int q = 0; q < 2; ++q) {
            const int idx = q * 256 + t;
            const int row = idx >> 5;
            const int kf4 = idx & 31;
            *reinterpret_cast<f32x4*>(&A_lds[0][row][kf4 * 4]) = a_reg[q];
        }
        #pragma unroll
        for (int q = 0; q < 6; ++q) {
            const int idx = q * 256 + t;
            const int c   = idx >> 5;
            const int kf4 = idx & 31;
            *reinterpret_cast<f32x4*>(&B_lds[0][c][kf4 * 4]) = b_reg[q];
        }
    }

    float acc[2][3];
    #pragma unroll
    for (int ri = 0; ri < 2; ++ri)
        #pragma unroll
        for (int j = 0; j < 3; ++j) acc[ri][j] = 0.f;

    const int kb4 = kgrp * 16;                 // this group's kk4 window

    for (int s = 0; s < GNSTEP; ++s) {
        __syncthreads();

        // Prefetch step s+1 into regs (overlaps with compute below).
        if (s + 1 < GNSTEP) {
            const int k0 = (s + 1) * GBK;
            #pragma unroll
            for (int q = 0; q < 2; ++q) {
                const int idx = q * 256 + t;
                const int row = idx >> 5;
                const int kf4 = idx & 31;
                a_reg[q] = hs4[(size_t)(row0 + row) * (H_DIM / 4) + (k0 >> 2) + kf4];
            }
            #pragma unroll
            for (int q = 0; q < 6; ++q) {
                const int idx = q * 256 + t;
                const int c   = idx >> 5;
                const int kf4 = idx & 31;
                b_reg[q] = *reinterpret_cast<const f32x4*>(
                    Wh + (size_t)c * TWO_H + k0 + kf4 * 4);
            }
        }

        // Compute step s from LDS (group-local kk4 window).
        const int buf = s & 1;
        #pragma unroll
        for (int kk4 = 0; kk4 < GBK / 4 / 2; ++kk4) {
            const int kz = (kb4 + kk4) * 4;
            f32x4 a[2], b[3];
            #pragma unroll
            for (int ri = 0; ri < 2; ++ri)
                a[ri] = *reinterpret_cast<const f32x4*>(&A_lds[buf][rs * 2 + ri][kz]);
            #pragma unroll
            for (int j = 0; j < 3; ++j)
                b[j] = *reinterpret_cast<const f32x4*>(&B_lds[buf][cs * 3 + j][kz]);
            #pragma unroll
            for (int ri = 0; ri < 2; ++ri)
                #pragma unroll
                for (int j = 0; j < 3; ++j) {
                    acc[ri][j] += a[ri].x * b[j].x;
                    acc[ri][j] += a[ri].y * b[j].y;
                    acc[ri][j] += a[ri].z * b[j].z;
                    acc[ri][j] += a[ri].w * b[j].w;
                }
        }

        __syncthreads();

        // Write prefetched regs into the other LDS buffer.
        if (s + 1 < GNSTEP) {
            const int buf2 = (s + 1) & 1;
            #pragma unroll
            for (int q = 0; q < 2; ++q) {
                const int idx = q * 256 + t;
                const int row = idx >> 5;
                const int kf4 = idx & 31;
                *reinterpret_cast<f32x4*>(&A_lds[buf2][row][kf4 * 4]) = a_reg[q];
            }
            #pragma unroll
            for (int q = 0; q < 6; ++q) {
                const int idx = q * 256 + t;
                const int c   = idx >> 5;
                const int kf4 = idx & 31;
                *reinterpret_cast<f32x4*>(&B_lds[buf2][c][kf4 * 4]) = b_reg[q];
            }
        }
    }

    // ---- in-block k-merge (no global partials, no second kernel) ----
    __syncthreads();
    if (kgrp == 1) {
        #pragma unroll
        for (int ri = 0; ri < 2; ++ri)
            #pragma unroll
            for (int j = 0; j < 3; ++j)
                mtile[rs * 2 + ri][cs * 3 + j] = acc[ri][j];
    }
    __syncthreads();
    if (kgrp == 0) {
        #pragma unroll
        for (int ri = 0; ri < 2; ++ri)
            #pragma unroll
            for (int j = 0; j < 3; ++j)
                mtile[rs * 2 + ri][cs * 3 + j] += acc[ri][j];
    }
    __syncthreads();

    // Coalesced write: 192 f32x4 -> proj[half][row0..+16][0..48).
    if (t < GBM * 12) {
        const int row = t / 12;
        const int c4  = t % 12;
        const f32x4 v = *reinterpret_cast<const f32x4*>(&mtile[row][c4 * 4]);
        reinterpret_cast<f32x4*>(proj)[(size_t)half * (NROWS * 12)
                                       + (size_t)(row0 + row) * 12 + c4] = v;
    }
}

// ---------------------------------------------------------------------------
// Kernel 2: out[b,i,j,c] = proj_i[b,i,c] + proj_j[b,j,c] + bias[c]
// R4/R11 version (best measured): one block per (b,i), 2048 x 256.
// ---------------------------------------------------------------------------
__global__ __launch_bounds__(256) void bcast_kernel(const float* __restrict__ proj,
                                                    const float* __restrict__ bias,
                                                    float* __restrict__ out) {
    const int gi = blockIdx.x;          // b*512 + i
    const int b  = gi >> 9;

    __shared__ f32x4 rowi[C_DIM / 4];   // proj_i[b,i,:] + bias  (12 f32x4)

    const int t = threadIdx.x;
    if (t < C_DIM / 4) {
        f32x4 pi = reinterpret_cast<const f32x4*>(proj + (size_t)gi * C_DIM)[t];
        f32x4 bb = reinterpret_cast<const f32x4*>(bias)[t];
        rowi[t] = pi + bb;
    }
    __syncthreads();

    const f32x4* __restrict__ pj =
        reinterpret_cast<const f32x4*>(proj + (size_t)NROWS * C_DIM
                                            + (size_t)b * 512 * C_DIM);
    f32x4* __restrict__ o =
        reinterpret_cast<f32x4*>(out) + (size_t)gi * 6144;

    #pragma unroll
    for (int it = 0; it < 24; ++it) {
        const int p  = it * 256 + t;
        o[p] = pj[p] + rowi[p % 12];
    }
}

extern "C" void kernel_launch(void* const* d_in, const int* in_sizes, int n_in,
                              void* d_out, int out_size, void* d_ws, size_t ws_size,
                              hipStream_t stream) {
    const float* hs   = (const float*)d_in[0];   // (4, 512, 768) f32
    const float* W    = (const float*)d_in[1];   // (48, 1536)    f32
    const float* bias = (const float*)d_in[2];   // (48,)         f32
    float* out  = (float*)d_out;                 // (4,512,512,48) f32
    float* proj = (float*)d_ws;                  // 786 KB in workspace

    // Two dispatches, no partials, no memsets, no atomics, no coop launch.
    gemm_kernel<<<dim3(256), 256, 0, stream>>>(hs, W, proj);
    bcast_kernel<<<dim3(NROWS), 256, 0, stream>>>(proj, bias, out);
}

// Round 13
// 42.581 us; speedup vs baseline: 9.2471x; 1.1220x over previous
//
#include <hip/hip_runtime.h>

typedef float  f32x4  __attribute__((ext_vector_type(4)));
typedef short  bf16x4 __attribute__((ext_vector_type(4)));
typedef short  bf16x8 __attribute__((ext_vector_type(8)));

// Problem dims (fixed by reference): bs=4, L=512, H=768, C=48
#define H_DIM 768
#define C_DIM 48
#define NROWS 2048          // bs * L
#define TWO_H 1536

// MFMA gemm geometry: 256 blocks = 128 rowgroups x 2 halves; 4 waves/block.
#define GBM 16              // rows per block
#define KH  384             // k staged per half-pass (two passes = K=768)
#define AST 392             // padded bf16 row stride (784 B; 196w%32=4 -> <=4-way)
#define MT_LD 52            // merge tile row stride (f32)

__device__ __forceinline__ unsigned short f2bf(float f) {   // RNE f32->bf16
    unsigned x = __float_as_uint(f);
    return (unsigned short)((x + 0x7fffu + ((x >> 16) & 1u)) >> 16);
}

// ---------------------------------------------------------------------------
// Kernel 1: proj GEMM via MFMA (bf16 inputs, f32 accum).
//   block(rg, half): rows rg*16..+16, cols half*48..+48; 256 thr = 4 waves.
//   Stage K in two 384-halves: f32 global load -> cvt bf16 -> LDS
//   (A[16][392], B[48][392], 50.2 KB). Wave w computes k in [w*96, w*96+96)
//   per half: 3 k-steps x 3 col-tiles = 9 mfma_f32_16x16x32_bf16; 18 total.
//   Frag layout: m/n = lane&15; k = 4*(lane>>4) + (j&3) + 16*(j>>2).
//   C/D: col = lane&15, row = (lane>>4)*4 + reg (m89-verified).
//   4-wave k-partials merged through an LDS tile aliased over A/B.
// ---------------------------------------------------------------------------
__global__ __launch_bounds__(256) void gemm_kernel(const float* __restrict__ hs,
                                                   const float* __restrict__ W,
                                                   float* __restrict__ proj) {
    __shared__ __align__(16) char smem[50176];
    unsigned short* Ab = (unsigned short*)smem;           // [16][392] bf16
    unsigned short* Bb = Ab + GBM * AST;                  // [48][392] bf16
    float*          mt = (float*)smem;                    // [4][16][52] f32 (aliased)

    const int t    = threadIdx.x;
    const int half = blockIdx.x & 1;
    const int rg   = blockIdx.x >> 1;                     // 0..127
    const int row0 = rg * GBM;

    const int w    = t >> 6;                              // wave 0..3
    const int lane = t & 63;
    const int g    = lane >> 4;                           // 0..3
    const int m    = lane & 15;                           // 0..15

    const f32x4* __restrict__ hs4 = reinterpret_cast<const f32x4*>(hs);
    const f32x4* __restrict__ Wv4 = reinterpret_cast<const f32x4*>(W);

    f32x4 acc[3];
    #pragma unroll
    for (int tc = 0; tc < 3; ++tc) acc[tc] = (f32x4){0.f, 0.f, 0.f, 0.f};

    #pragma unroll
    for (int h = 0; h < 2; ++h) {
        if (h) __syncthreads();   // all waves done reading previous half

        // ---- stage half h: A (16x384) + B (48x384), f32 -> bf16 -> LDS ----
        #pragma unroll
        for (int q = 0; q < 6; ++q) {                     // hs: 1536 f32x4
            const int idx = q * 256 + t;
            const int row = idx / 96;
            const int kf4 = idx % 96;
            const f32x4 v = hs4[(size_t)(row0 + row) * 192 + h * 96 + kf4];
            bf16x4 p = {(short)f2bf(v.x), (short)f2bf(v.y),
                        (short)f2bf(v.z), (short)f2bf(v.w)};
            *reinterpret_cast<bf16x4*>(Ab + row * AST + kf4 * 4) = p;
        }
        #pragma unroll
        for (int q = 0; q < 18; ++q) {                    // W-half: 4608 f32x4
            const int idx = q * 256 + t;
            const int c   = idx / 96;
            const int kf4 = idx % 96;
            const f32x4 v = Wv4[(size_t)c * 384 + half * 192 + h * 96 + kf4];
            bf16x4 p = {(short)f2bf(v.x), (short)f2bf(v.y),
                        (short)f2bf(v.z), (short)f2bf(v.w)};
            *reinterpret_cast<bf16x4*>(Bb + c * AST + kf4 * 4) = p;
        }
        __syncthreads();

        // ---- compute half h: wave w covers local k in [w*96, w*96+96) ----
        #pragma unroll
        for (int ks = 0; ks < 3; ++ks) {
            const int klo = w * 96 + ks * 32 + 4 * g;
            const bf16x4 alo = *reinterpret_cast<const bf16x4*>(Ab + m * AST + klo);
            const bf16x4 ahi = *reinterpret_cast<const bf16x4*>(Ab + m * AST + klo + 16);
            bf16x8 af;
            #pragma unroll
            for (int i = 0; i < 4; ++i) { af[i] = alo[i]; af[i + 4] = ahi[i]; }

            #pragma unroll
            for (int tc = 0; tc < 3; ++tc) {
                const unsigned short* bp = Bb + (tc * 16 + m) * AST + klo;
                const bf16x4 blo = *reinterpret_cast<const bf16x4*>(bp);
                const bf16x4 bhi = *reinterpret_cast<const bf16x4*>(bp + 16);
                bf16x8 bfr;
                #pragma unroll
                for (int i = 0; i < 4; ++i) { bfr[i] = blo[i]; bfr[i + 4] = bhi[i]; }
                acc[tc] = __builtin_amdgcn_mfma_f32_16x16x32_bf16(af, bfr, acc[tc], 0, 0, 0);
            }
        }
    }

    // ---- merge 4 waves' k-partials (mt aliases A/B; all reads are done) ----
    __syncthreads();
    #pragma unroll
    for (int tc = 0; tc < 3; ++tc)
        #pragma unroll
        for (int r = 0; r < 4; ++r)
            mt[w * (GBM * MT_LD) + (g * 4 + r) * MT_LD + tc * 16 + m] = acc[tc][r];
    __syncthreads();

    if (t < GBM * 12) {                                   // 192 f32x4 outputs
        const int row = t / 12;
        const int c4  = t % 12;
        f32x4 s = *reinterpret_cast<const f32x4*>(mt + row * MT_LD + c4 * 4);
        #pragma unroll
        for (int ww = 1; ww < 4; ++ww)
            s += *reinterpret_cast<const f32x4*>(mt + ww * (GBM * MT_LD) + row * MT_LD + c4 * 4);
        reinterpret_cast<f32x4*>(proj)[(size_t)half * (NROWS * 12)
                                       + (size_t)(row0 + row) * 12 + c4] = s;
    }
}

// ---------------------------------------------------------------------------
// Kernel 2: out[b,i,j,c] = proj_i[b,i,c] + proj_j[b,j,c] + bias[c]
// R4/R12 version (best measured, untouched control): one block per (b,i).
// ---------------------------------------------------------------------------
__global__ __launch_bounds__(256) void bcast_kernel(const float* __restrict__ proj,
                                                    const float* __restrict__ bias,
                                                    float* __restrict__ out) {
    const int gi = blockIdx.x;          // b*512 + i
    const int b  = gi >> 9;

    __shared__ f32x4 rowi[C_DIM / 4];   // proj_i[b,i,:] + bias  (12 f32x4)

    const int t = threadIdx.x;
    if (t < C_DIM / 4) {
        f32x4 pi = reinterpret_cast<const f32x4*>(proj + (size_t)gi * C_DIM)[t];
        f32x4 bb = reinterpret_cast<const f32x4*>(bias)[t];
        rowi[t] = pi + bb;
    }
    __syncthreads();

    const f32x4* __restrict__ pj =
        reinterpret_cast<const f32x4*>(proj + (size_t)NROWS * C_DIM
                                            + (size_t)b * 512 * C_DIM);
    f32x4* __restrict__ o =
        reinterpret_cast<f32x4*>(out) + (size_t)gi * 6144;

    #pragma unroll
    for (int it = 0; it < 24; ++it) {
        const int p  = it * 256 + t;
        o[p] = pj[p] + rowi[p % 12];
    }
}

extern "C" void kernel_launch(void* const* d_in, const int* in_sizes, int n_in,
                              void* d_out, int out_size, void* d_ws, size_t ws_size,
                              hipStream_t stream) {
    const float* hs   = (const float*)d_in[0];   // (4, 512, 768) f32
    const float* W    = (const float*)d_in[1];   // (48, 1536)    f32
    const float* bias = (const float*)d_in[2];   // (48,)         f32
    float* out  = (float*)d_out;                 // (4,512,512,48) f32
    float* proj = (float*)d_ws;                  // 786 KB in workspace

    gemm_kernel<<<dim3(256), 256, 0, stream>>>(hs, W, proj);
    bcast_kernel<<<dim3(NROWS), 256, 0, stream>>>(proj, bias, out);
}